// Round 1
// baseline (92.044 us; speedup 1.0000x reference)
//
#include <hip/hip_runtime.h>

#define IN_H 200
#define IN_W 200
#define NCH  256
#define NROI 512
#define OUT_HW 49

__global__ __launch_bounds__(256) void roi_align_kernel(
    const float* __restrict__ input,
    const float* __restrict__ rois,
    float* __restrict__ out) {
  const int blk  = blockIdx.x;
  const int k    = blk >> 6;          // roi index (64 channel-groups per roi)
  const int cg   = blk & 63;
  const int wave = threadIdx.x >> 6;  // 0..3
  const int lane = threadIdx.x & 63;
  const int c    = (cg << 2) + wave;  // channel 0..255

  const float* r = rois + k * 5;
  const int   b   = (int)r[0];
  const float x1s = r[1] * 0.25f;
  const float y1s = r[2] * 0.25f;
  const float x2s = r[3] * 0.25f;
  const float y2s = r[4] * 0.25f;
  const float roi_w = fmaxf(x2s - x1s, 1.0f);
  const float roi_h = fmaxf(y2s - y1s, 1.0f);
  const float bw = roi_w / 7.0f;
  const float bh = roi_h / 7.0f;

  // validity: coords monotonic in (p,i) -> check extreme sample coords only
  const float ymin = y1s + (bh * 0.5f) * 0.5f;
  const float xmin = x1s + (bw * 0.5f) * 0.5f;
  const float ymax = y1s + (bh * 6.0f + (bh * 0.5f) * 1.5f);
  const float xmax = x1s + (bw * 6.0f + (bw * 0.5f) * 1.5f);
  const bool valid = (ymin >= -1.0f) && (ymax <= (float)IN_H) &&
                     (xmin >= -1.0f) && (xmax <= (float)IN_W);

  if (lane < OUT_HW) {
    const int ph = lane / 7;
    const int pw = lane - ph * 7;
    const float* plane = input + ((size_t)(b * NCH + c)) * (IN_H * IN_W);

    const float ybase = y1s + bh * (float)ph;
    const float xbase = x1s + bw * (float)pw;

    float acc = 0.0f;
#pragma unroll
    for (int iy = 0; iy < 2; ++iy) {
      const float y  = ybase + (bh * 0.5f) * ((float)iy + 0.5f);
      const float yc = fminf(fmaxf(y, 0.0f), (float)(IN_H - 1));
      const float ylf = floorf(yc);
      const int   yl  = (int)ylf;
      const int   yh  = min(yl + 1, IN_H - 1);
      const float ly  = yc - ylf;
      const float hy  = 1.0f - ly;
#pragma unroll
      for (int ix = 0; ix < 2; ++ix) {
        const float x  = xbase + (bw * 0.5f) * ((float)ix + 0.5f);
        const float xc = fminf(fmaxf(x, 0.0f), (float)(IN_W - 1));
        const float xlf = floorf(xc);
        const int   xl  = (int)xlf;
        const int   xh  = min(xl + 1, IN_W - 1);
        const float lx  = xc - xlf;
        const float hx  = 1.0f - lx;

        const float* row_l = plane + yl * IN_W;
        const float* row_h = plane + yh * IN_W;
        const float v1 = row_l[xl];
        const float v2 = row_l[xh];
        const float v3 = row_h[xl];
        const float v4 = row_h[xh];

        acc += hy * hx * v1 + hy * lx * v2 + ly * hx * v3 + ly * lx * v4;
      }
    }
    const size_t oidx = ((size_t)k * NCH + c) * OUT_HW + lane;
    out[oidx] = valid ? acc * 0.25f : 0.0f;
  }
}

extern "C" void kernel_launch(void* const* d_in, const int* in_sizes, int n_in,
                              void* d_out, int out_size, void* d_ws, size_t ws_size,
                              hipStream_t stream) {
  const float* input = (const float*)d_in[0];
  const float* rois  = (const float*)d_in[1];
  float* out = (float*)d_out;

  const int blocks = NROI * (NCH / 4);  // 32768
  roi_align_kernel<<<blocks, 256, 0, stream>>>(input, rois, out);
}